// Round 2
// baseline (225.372 us; speedup 1.0000x reference)
//
#include <hip/hip_runtime.h>
#include <math.h>

#define DI __device__ __forceinline__

typedef short s16x8 __attribute__((ext_vector_type(8)));
typedef float f32x4 __attribute__((ext_vector_type(4)));

constexpr float MARKOFF_ = -100000000.0f;
constexpr float INVSCALE_ = 0.088388347648318447f;  // 1/sqrt(128)

// ---------- helpers ----------
DI s16x8 bc(uint4 u) { return __builtin_bit_cast(s16x8, u); }
DI unsigned short f2bf(float f) {  // RNE f32 -> bf16
  unsigned u = __float_as_uint(f);
  return (unsigned short)((u + 0x7FFFu + ((u >> 16) & 1u)) >> 16);
}
DI float bf2f(unsigned short h) { return __uint_as_float(((unsigned)h) << 16); }

DI void load16(float* dst, const float* src) {
  #pragma unroll
  for (int c = 0; c < 4; ++c) {
    float4 v = reinterpret_cast<const float4*>(src)[c];
    dst[c * 4 + 0] = v.x; dst[c * 4 + 1] = v.y;
    dst[c * 4 + 2] = v.z; dst[c * 4 + 3] = v.w;
  }
}

DI float dotw4(const float4* w4, const float* x) {
  float s = 0.f;
  #pragma unroll
  for (int c = 0; c < 4; ++c) {
    float4 w = w4[c];
    s = fmaf(w.x, x[4*c], fmaf(w.y, x[4*c+1], fmaf(w.z, x[4*c+2], fmaf(w.w, x[4*c+3], s))));
  }
  return s;
}

// pack y[16] fp32 -> row [hi d0..15 | lo d0..15] as 4x uint4 (32 bf16)
DI void packstore(ushort* dst, const float* y) {
  ushort hs[16];
  #pragma unroll
  for (int d = 0; d < 16; ++d) hs[d] = f2bf(y[d]);
  unsigned hi[8], lo[8];
  #pragma unroll
  for (int i = 0; i < 8; ++i) {
    hi[i] = (unsigned)hs[2*i] | ((unsigned)hs[2*i+1] << 16);
    float l0 = y[2*i]   - bf2f(hs[2*i]);
    float l1 = y[2*i+1] - bf2f(hs[2*i+1]);
    lo[i] = (unsigned)f2bf(l0) | ((unsigned)f2bf(l1) << 16);
  }
  uint4* p = (uint4*)dst;
  p[0] = make_uint4(hi[0], hi[1], hi[2], hi[3]);
  p[1] = make_uint4(hi[4], hi[5], hi[6], hi[7]);
  p[2] = make_uint4(lo[0], lo[1], lo[2], lo[3]);
  p[3] = make_uint4(lo[4], lo[5], lo[6], lo[7]);
}

// ---------------- Kernel 1: QKV projection -> packed hi/lo bf16 ----------------
// grid 192 = SL(12) x nchunk(16 of 32 n). 256 thr: th = tid&15, nl = tid>>4 (+16).
// Qp/Kp row (SL,n,th): 32 bf16 = [hi(16)|lo(16)].  Vt[(SL*16+th)*16+d][512 n] bf16.
__global__ __launch_bounds__(256) void k_proj(
    const float* __restrict__ vals, const float* __restrict__ keys,
    const float* __restrict__ qry, const float* __restrict__ Wv,
    const float* __restrict__ Wk, const float* __restrict__ Wq,
    ushort* __restrict__ Qp, ushort* __restrict__ Kp, ushort* __restrict__ Vt) {
  __shared__ float wlds[768];
  int blk = blockIdx.x;
  int nc = blk & 15, SL = blk >> 4;
  int b = SL / 6, t2 = SL % 6;
  int tid = threadIdx.x;
  wlds[tid] = Wq[tid];
  wlds[256 + tid] = Wk[tid];
  wlds[512 + tid] = Wv[tid];
  __syncthreads();
  int th = tid & 15, nl0 = tid >> 4;
  int t = 2 * t2 + (th >> 3), h = th & 7;
  for (int it = 0; it < 2; ++it) {
    int n = nc * 32 + it * 16 + nl0;
    size_t ioff = ((size_t)(b * 512 + n) * 12 + t) * 128 + h * 16;
    float xq[16], xk[16], xv[16], y[16];
    load16(xq, qry + ioff);
    load16(xk, keys + ioff);
    load16(xv, vals + ioff);
    size_t orow = ((size_t)(SL * 512 + n) * 16 + th) * 32;
    #pragma unroll
    for (int d = 0; d < 16; ++d) y[d] = dotw4((const float4*)&wlds[d * 16], xq);
    packstore(Qp + orow, y);
    #pragma unroll
    for (int d = 0; d < 16; ++d) y[d] = dotw4((const float4*)&wlds[256 + d * 16], xk);
    packstore(Kp + orow, y);
    #pragma unroll
    for (int d = 0; d < 16; ++d) y[d] = dotw4((const float4*)&wlds[512 + d * 16], xv);
    #pragma unroll
    for (int d = 0; d < 16; ++d)
      Vt[((size_t)(SL * 16 + th) * 16 + d) * 512 + n] = f2bf(y[d]);
  }
}

// ---------------- Kernel 2: column sums of exp (softmax denom, q-split) --------
// grid 768 = qs(4) x kc(16 of 32 k) x SL(12). 4 waves x 4 th. M=q, N=k orientation.
__global__ __launch_bounds__(256) void k_colsum(
    const ushort* __restrict__ Qp, const ushort* __restrict__ Kp,
    const float* __restrict__ mask, float* __restrict__ cs) {
  int blk = blockIdx.x;
  int qs = blk & 3, kc = (blk >> 2) & 15, SL = blk >> 6;
  int tid = threadIdx.x;
  int l = tid & 63, wv = tid >> 6, c = l & 15, g = l >> 4, thb = wv * 4;
  uint4 zz = make_uint4(0, 0, 0, 0);
  s16x8 Bk1[2][4], Bk2[2][4];  // B = K: [khi|khi] and [klo|0]
  #pragma unroll
  for (int e = 0; e < 2; ++e) {
    int kb = kc * 32 + e * 16;
    #pragma unroll
    for (int j = 0; j < 4; ++j) {
      const uint4* row = (const uint4*)(Kp + ((size_t)(SL * 512 + kb + c) * 16 + thb + j) * 32);
      Bk1[e][j] = bc(row[g & 1]);
      Bk2[e][j] = bc(g < 2 ? row[2 + (g & 1)] : zz);
    }
  }
  float sum[2][4] = {{0.f, 0.f, 0.f, 0.f}, {0.f, 0.f, 0.f, 0.f}};
  for (int qtl = 0; qtl < 8; ++qtl) {
    int qb = qs * 128 + qtl * 16;
    float m[2][4];
    #pragma unroll
    for (int e = 0; e < 2; ++e) {
      int kb = kc * 32 + e * 16;
      #pragma unroll
      for (int r = 0; r < 4; ++r)
        m[e][r] = mask[(size_t)(qb + 4 * g + r) * 512 + kb + c];
    }
    #pragma unroll
    for (int j = 0; j < 4; ++j) {
      const uint4* qrow = (const uint4*)(Qp + ((size_t)(SL * 512 + qb + c) * 16 + thb + j) * 32);
      s16x8 A1 = bc(qrow[g]);        // [qhi|qlo]
      s16x8 A2 = bc(qrow[g & 1]);    // [qhi|qhi]
      #pragma unroll
      for (int e = 0; e < 2; ++e) {
        f32x4 C = __builtin_amdgcn_mfma_f32_16x16x32_bf16(A1, Bk1[e][j], (f32x4){0.f,0.f,0.f,0.f}, 0, 0, 0);
        C = __builtin_amdgcn_mfma_f32_16x16x32_bf16(A2, Bk2[e][j], C, 0, 0, 0);
        #pragma unroll
        for (int r = 0; r < 4; ++r) {
          float Em = m[e][r] > 0.5f ? C[r] : MARKOFF_;  // exact select (no fma w/ 1e8!)
          float x = fminf(fmaxf(Em * INVSCALE_, -5.f), 5.f);
          sum[e][j] += __expf(x);
        }
      }
    }
  }
  #pragma unroll
  for (int e = 0; e < 2; ++e)
    #pragma unroll
    for (int j = 0; j < 4; ++j) {
      float s = sum[e][j];
      s += __shfl_xor(s, 16, 64);
      s += __shfl_xor(s, 32, 64);
      if (l < 16)
        cs[((size_t)(qs * 12 + SL) * 16 + thb + j) * 512 + kc * 32 + e * 16 + c] = s;
    }
}

// ---------------- Kernel 3: inv = 1/sum of 4 q-split partials ----------------
__global__ __launch_bounds__(256) void k_inv(const float* __restrict__ cs,
                                             float* __restrict__ inv) {
  int id = blockIdx.x * 256 + threadIdx.x;  // 98304 total
  float s = cs[id] + cs[id + 98304] + cs[id + 196608] + cs[id + 294912];
  inv[id] = 1.0f / s;
}

// ---------------- Kernel 4: attention write + A@V (MFMA) ----------------
// grid 384*KS. Block = (SL, qtile16, ksp). 4 waves x 4 th. Energies M=k,N=q.
__global__ __launch_bounds__(256) void k_attn(
    const ushort* __restrict__ Qp, const ushort* __restrict__ Kp,
    const ushort* __restrict__ Vt, const float* __restrict__ mask,
    const float* __restrict__ inv, float* __restrict__ Aout,
    float* __restrict__ Oh, int KS) {
  __shared__ ushort alds[16 * 16 * 40];  // [th][q16][40] (32 used, pad->80B rows), 20 KiB
  int blk = blockIdx.x;
  int ksp = blk & (KS - 1);
  int rest = blk / KS;
  int qt = rest & 31, SL = rest >> 5;
  int b = SL / 6, t2 = SL % 6;
  int qb = qt * 16;
  int tid = threadIdx.x;
  int l = tid & 63, wv = tid >> 6, c = l & 15, g = l >> 4, thb = wv * 4;
  uint4 zz = make_uint4(0, 0, 0, 0);
  s16x8 Bq1[4], Bq2[4];  // B = Q: [qhi|qhi], [qlo|0]
  #pragma unroll
  for (int j = 0; j < 4; ++j) {
    const uint4* row = (const uint4*)(Qp + ((size_t)(SL * 512 + qb + c) * 16 + thb + j) * 32);
    Bq1[j] = bc(row[g & 1]);
    Bq2[j] = bc(g < 2 ? row[2 + (g & 1)] : zz);
  }
  f32x4 O[4];
  #pragma unroll
  for (int j = 0; j < 4; ++j) O[j] = (f32x4){0.f, 0.f, 0.f, 0.f};

  int nch = 16 / KS;
  for (int cc = 0; cc < nch; ++cc) {
    int kch = ksp * (512 / KS) + cc * 32;
    #pragma unroll
    for (int e = 0; e < 2; ++e) {
      int kb = kch + e * 16;
      float4 m4 = *(const float4*)(mask + (size_t)(qb + c) * 512 + kb + 4 * g);
      float m[4] = {m4.x, m4.y, m4.z, m4.w};
      float p[4][4];
      #pragma unroll
      for (int j = 0; j < 4; ++j) {
        const uint4* krow = (const uint4*)(Kp + ((size_t)(SL * 512 + kb + c) * 16 + thb + j) * 32);
        s16x8 A1 = bc(krow[g]);      // [khi|klo]
        s16x8 A2 = bc(krow[g & 1]);  // [khi|khi]
        f32x4 C = __builtin_amdgcn_mfma_f32_16x16x32_bf16(A1, Bq1[j], (f32x4){0.f,0.f,0.f,0.f}, 0, 0, 0);
        C = __builtin_amdgcn_mfma_f32_16x16x32_bf16(A2, Bq2[j], C, 0, 0, 0);
        float4 i4 = *(const float4*)(inv + (size_t)(SL * 16 + thb + j) * 512 + kb + 4 * g);
        float iv[4] = {i4.x, i4.y, i4.z, i4.w};
        #pragma unroll
        for (int r = 0; r < 4; ++r) {
          float Em = m[r] > 0.5f ? C[r] : MARKOFF_;
          float x = fminf(fmaxf(Em * INVSCALE_, -5.f), 5.f);
          p[j][r] = __expf(x) * iv[r];
        }
        unsigned d0 = (unsigned)f2bf(p[j][0]) | ((unsigned)f2bf(p[j][1]) << 16);
        unsigned d1 = (unsigned)f2bf(p[j][2]) | ((unsigned)f2bf(p[j][3]) << 16);
        *(uint2*)&alds[((thb + j) * 16 + c) * 40 + e * 16 + 4 * g] = make_uint2(d0, d1);
      }
      // attention stores: 16B/lane, th-run contiguous; 64B lines fully covered by the 4 waves
      #pragma unroll
      for (int r = 0; r < 4; ++r) {
        size_t ai = ((size_t)(b * 512 + qb + c) * 512 + kb + 4 * g + r) * 96 + t2 * 16 + thb;
        *(float4*)(Aout + ai) = make_float4(p[0][r], p[1][r], p[2][r], p[3][r]);
      }
    }
    // A@V over this 32-k chunk (A from wave-private LDS transpose, M=q,N=d)
    #pragma unroll
    for (int j = 0; j < 4; ++j) {
      s16x8 a_op = bc(*(const uint4*)&alds[((thb + j) * 16 + c) * 40 + g * 8]);
      s16x8 v_op = bc(*(const uint4*)(Vt + ((size_t)(SL * 16 + thb + j) * 16 + c) * 512 + kch + g * 8));
      O[j] = __builtin_amdgcn_mfma_f32_16x16x32_bf16(a_op, v_op, O[j], 0, 0, 0);
    }
  }
  #pragma unroll
  for (int j = 0; j < 4; ++j) {
    int th = thb + j, t = 2 * t2 + (th >> 3), h = th & 7;
    float* op = Oh + (size_t)ksp * 1572864;
    #pragma unroll
    for (int r = 0; r < 4; ++r)
      op[((size_t)(b * 512 + qb + 4 * g + r) * 12 + t) * 128 + h * 16 + c] = O[j][r];
  }
}

// ---------------- Kernel 5: out = Oh @ Wo^T + bo ----------------
__global__ __launch_bounds__(128) void k_outproj(
    const float* __restrict__ Oh, const float* __restrict__ Wo,
    const float* __restrict__ bo, float* __restrict__ out, int KS) {
  __shared__ float xr[12 * 128];
  int bn = blockIdx.x;
  int b = bn >> 9, n = bn & 511;
  int col = threadIdx.x;
  for (int i = col; i < 1536; i += 128) {
    float s = 0.f;
    for (int sl = 0; sl < KS; ++sl)
      s += Oh[(size_t)sl * 1572864 + (size_t)(b * 512 + n) * 1536 + i];
    xr[i] = s;
  }
  __syncthreads();
  float acc[12];
  float bias = bo[col];
  #pragma unroll
  for (int rr = 0; rr < 12; ++rr) acc[rr] = bias;
  const float4* wrow = reinterpret_cast<const float4*>(Wo + (size_t)col * 128);
  #pragma unroll 8
  for (int jc = 0; jc < 32; ++jc) {
    float4 w = wrow[jc];
    #pragma unroll
    for (int rr = 0; rr < 12; ++rr) {
      const float* x = &xr[rr * 128 + jc * 4];
      acc[rr] = fmaf(w.x, x[0], fmaf(w.y, x[1], fmaf(w.z, x[2], fmaf(w.w, x[3], acc[rr]))));
    }
  }
  size_t obase = ((size_t)(b * 512 + n)) * 1536;
  #pragma unroll
  for (int rr = 0; rr < 12; ++rr) out[obase + rr * 128 + col] = acc[rr];
}

extern "C" void kernel_launch(void* const* d_in, const int* in_sizes, int n_in,
                              void* d_out, int out_size, void* d_ws, size_t ws_size,
                              hipStream_t stream) {
  (void)in_sizes; (void)n_in; (void)out_size;
  const float* vals = (const float*)d_in[0];
  const float* keys = (const float*)d_in[1];
  const float* qry  = (const float*)d_in[2];
  const float* mask = (const float*)d_in[3];
  const float* Wv = (const float*)d_in[4];
  const float* Wk = (const float*)d_in[5];
  const float* Wq = (const float*)d_in[6];
  const float* Wo = (const float*)d_in[7];
  const float* bo = (const float*)d_in[8];
  float* out = (float*)d_out;
  float* Aout = out + 1572864;  // attention after `out`

  ushort* Qp = (ushort*)d_ws;           // 3,145,728 bf16
  ushort* Kp = Qp + 3145728;            // 3,145,728 bf16
  ushort* Vt = Kp + 3145728;            // 1,572,864 bf16
  float* cs  = (float*)(Vt + 1572864);  // 393,216 f32
  float* inv = cs + 393216;             // 98,304 f32
  float* Oh  = inv + 98304;             // KS x 1,572,864 f32

  const size_t BASE = 17694720;  // bytes before Oh
  int KS = 1;
  if (ws_size >= BASE + 4ull * 6291456) KS = 4;
  else if (ws_size >= BASE + 2ull * 6291456) KS = 2;

  k_proj<<<192, 256, 0, stream>>>(vals, keys, qry, Wv, Wk, Wq, Qp, Kp, Vt);
  k_colsum<<<768, 256, 0, stream>>>(Qp, Kp, mask, cs);
  k_inv<<<384, 256, 0, stream>>>(cs, inv);
  k_attn<<<384 * KS, 256, 0, stream>>>(Qp, Kp, Vt, mask, inv, Aout, Oh, KS);
  k_outproj<<<1024, 128, 0, stream>>>(Oh, Wo, bo, out, KS);
}

// Round 4
// 192.373 us; speedup vs baseline: 1.1715x; 1.1715x over previous
//
#include <hip/hip_runtime.h>
#include <math.h>

#define DI __device__ __forceinline__

typedef short s16x8 __attribute__((ext_vector_type(8)));
typedef float f32x4 __attribute__((ext_vector_type(4)));

constexpr float MARKOFF_ = -100000000.0f;
constexpr float INVSCALE_ = 0.088388347648318447f;  // 1/sqrt(128)

// ---------- helpers ----------
DI s16x8 bc(uint4 u) { return __builtin_bit_cast(s16x8, u); }
DI unsigned short f2bf(float f) {  // RNE f32 -> bf16
  unsigned u = __float_as_uint(f);
  return (unsigned short)((u + 0x7FFFu + ((u >> 16) & 1u)) >> 16);
}
DI float bf2f(unsigned short h) { return __uint_as_float(((unsigned)h) << 16); }

DI void load16(float* dst, const float* src) {
  #pragma unroll
  for (int c = 0; c < 4; ++c) {
    float4 v = reinterpret_cast<const float4*>(src)[c];
    dst[c * 4 + 0] = v.x; dst[c * 4 + 1] = v.y;
    dst[c * 4 + 2] = v.z; dst[c * 4 + 3] = v.w;
  }
}

DI float dotw4(const float4* w4, const float* x) {
  float s = 0.f;
  #pragma unroll
  for (int c = 0; c < 4; ++c) {
    float4 w = w4[c];
    s = fmaf(w.x, x[4*c], fmaf(w.y, x[4*c+1], fmaf(w.z, x[4*c+2], fmaf(w.w, x[4*c+3], s))));
  }
  return s;
}

// pack y[16] fp32 -> row [hi d0..15 | lo d0..15] as 4x uint4 (32 bf16)
DI void packstore(ushort* dst, const float* y) {
  ushort hs[16];
  #pragma unroll
  for (int d = 0; d < 16; ++d) hs[d] = f2bf(y[d]);
  unsigned hi[8], lo[8];
  #pragma unroll
  for (int i = 0; i < 8; ++i) {
    hi[i] = (unsigned)hs[2*i] | ((unsigned)hs[2*i+1] << 16);
    float l0 = y[2*i]   - bf2f(hs[2*i]);
    float l1 = y[2*i+1] - bf2f(hs[2*i+1]);
    lo[i] = (unsigned)f2bf(l0) | ((unsigned)f2bf(l1) << 16);
  }
  uint4* p = (uint4*)dst;
  p[0] = make_uint4(hi[0], hi[1], hi[2], hi[3]);
  p[1] = make_uint4(hi[4], hi[5], hi[6], hi[7]);
  p[2] = make_uint4(lo[0], lo[1], lo[2], lo[3]);
  p[3] = make_uint4(lo[4], lo[5], lo[6], lo[7]);
}

// ---------------- Kernel 1: QKV projection -> packed hi/lo bf16 ----------------
// grid 192 = SL(12) x nchunk(16 of 32 n). Vt transposed via swizzled LDS tile.
__global__ __launch_bounds__(256) void k_proj(
    const float* __restrict__ vals, const float* __restrict__ keys,
    const float* __restrict__ qry, const float* __restrict__ Wv,
    const float* __restrict__ Wk, const float* __restrict__ Wq,
    ushort* __restrict__ Qp, ushort* __restrict__ Kp, ushort* __restrict__ Vt) {
  __shared__ float wlds[768];
  __shared__ ushort vtile[16 * 16 * 32];  // [th][d][n32], nl XOR-swizzled
  int blk = blockIdx.x;
  int nc = blk & 15, SL = blk >> 4;
  int b = SL / 6, t2 = SL % 6;
  int tid = threadIdx.x;
  wlds[tid] = Wq[tid];
  wlds[256 + tid] = Wk[tid];
  wlds[512 + tid] = Wv[tid];
  __syncthreads();
  int th = tid & 15, nl0 = tid >> 4;
  int t = 2 * t2 + (th >> 3), h = th & 7;
  int key = (th & 3) << 3;
  for (int it = 0; it < 2; ++it) {
    int nl = it * 16 + nl0;
    int n = nc * 32 + nl;
    size_t ioff = ((size_t)(b * 512 + n) * 12 + t) * 128 + h * 16;
    float xq[16], xk[16], xv[16], y[16];
    load16(xq, qry + ioff);
    load16(xk, keys + ioff);
    load16(xv, vals + ioff);
    size_t orow = ((size_t)(SL * 512 + n) * 16 + th) * 32;
    #pragma unroll
    for (int d = 0; d < 16; ++d) y[d] = dotw4((const float4*)&wlds[d * 16], xq);
    packstore(Qp + orow, y);
    #pragma unroll
    for (int d = 0; d < 16; ++d) y[d] = dotw4((const float4*)&wlds[256 + d * 16], xk);
    packstore(Kp + orow, y);
    #pragma unroll
    for (int d = 0; d < 16; ++d) y[d] = dotw4((const float4*)&wlds[512 + d * 16], xv);
    #pragma unroll
    for (int d = 0; d < 16; ++d) vtile[th * 512 + d * 32 + (nl ^ key)] = f2bf(y[d]);
  }
  __syncthreads();
  // coalesced Vt writeout: full 64B lines, 4 lanes per (th,d) row
  #pragma unroll
  for (int it2 = 0; it2 < 4; ++it2) {
    int f = tid + it2 * 256;
    int thd = f >> 2;        // (th*16+d)
    int thv = thd >> 4;
    int npp = f & 3;         // physical 8-run
    int npl = npp ^ (thv & 3);  // logical n-part
    uint4 v = *(const uint4*)&vtile[thd * 32 + npp * 8];
    *(uint4*)(Vt + (size_t)(SL * 256 + thd) * 512 + nc * 32 + npl * 8) = v;
  }
}

// ---------------- Kernel 2: column sums of exp (softmax denom, q-split) --------
__global__ __launch_bounds__(256) void k_colsum(
    const ushort* __restrict__ Qp, const ushort* __restrict__ Kp,
    const float* __restrict__ mask, float* __restrict__ cs) {
  int blk = blockIdx.x;
  int qs = blk & 3, kc = (blk >> 2) & 15, SL = blk >> 6;
  int tid = threadIdx.x;
  int l = tid & 63, wv = tid >> 6, c = l & 15, g = l >> 4, thb = wv * 4;
  uint4 zz = make_uint4(0, 0, 0, 0);
  s16x8 Bk1[2][4], Bk2[2][4];
  #pragma unroll
  for (int e = 0; e < 2; ++e) {
    int kb = kc * 32 + e * 16;
    #pragma unroll
    for (int j = 0; j < 4; ++j) {
      const uint4* row = (const uint4*)(Kp + ((size_t)(SL * 512 + kb + c) * 16 + thb + j) * 32);
      Bk1[e][j] = bc(row[g & 1]);
      Bk2[e][j] = bc(g < 2 ? row[2 + (g & 1)] : zz);
    }
  }
  float sum[2][4] = {{0.f, 0.f, 0.f, 0.f}, {0.f, 0.f, 0.f, 0.f}};
  for (int qtl = 0; qtl < 8; ++qtl) {
    int qb = qs * 128 + qtl * 16;
    float m[2][4];
    #pragma unroll
    for (int e = 0; e < 2; ++e) {
      int kb = kc * 32 + e * 16;
      #pragma unroll
      for (int r = 0; r < 4; ++r)
        m[e][r] = mask[(size_t)(qb + 4 * g + r) * 512 + kb + c];
    }
    #pragma unroll
    for (int j = 0; j < 4; ++j) {
      const uint4* qrow = (const uint4*)(Qp + ((size_t)(SL * 512 + qb + c) * 16 + thb + j) * 32);
      s16x8 A1 = bc(qrow[g]);
      s16x8 A2 = bc(qrow[g & 1]);
      #pragma unroll
      for (int e = 0; e < 2; ++e) {
        f32x4 C = __builtin_amdgcn_mfma_f32_16x16x32_bf16(A1, Bk1[e][j], (f32x4){0.f,0.f,0.f,0.f}, 0, 0, 0);
        C = __builtin_amdgcn_mfma_f32_16x16x32_bf16(A2, Bk2[e][j], C, 0, 0, 0);
        #pragma unroll
        for (int r = 0; r < 4; ++r) {
          float Em = m[e][r] > 0.5f ? C[r] : MARKOFF_;
          float x = fminf(fmaxf(Em * INVSCALE_, -5.f), 5.f);
          sum[e][j] += __expf(x);
        }
      }
    }
  }
  #pragma unroll
  for (int e = 0; e < 2; ++e)
    #pragma unroll
    for (int j = 0; j < 4; ++j) {
      float s = sum[e][j];
      s += __shfl_xor(s, 16, 64);
      s += __shfl_xor(s, 32, 64);
      if (l < 16)
        cs[((size_t)(qs * 12 + SL) * 16 + thb + j) * 512 + kc * 32 + e * 16 + c] = s;
    }
}

// ---------------- Kernel 3: inv = 1/sum of 4 q-split partials ----------------
__global__ __launch_bounds__(256) void k_inv(const float* __restrict__ cs,
                                             float* __restrict__ inv) {
  int id = blockIdx.x * 256 + threadIdx.x;
  float s = cs[id] + cs[id + 98304] + cs[id + 196608] + cs[id + 294912];
  inv[id] = 1.0f / s;
}

// ---------------- Kernel 4: attention (MFMA) + staged coalesced A-writes -------
// grid 384*KS. stage[kk][q][th]: word = kk*273 + q*17 + th  (35 KB)
__global__ __launch_bounds__(256) void k_attn(
    const ushort* __restrict__ Qp, const ushort* __restrict__ Kp,
    const ushort* __restrict__ Vt, const float* __restrict__ mask,
    const float* __restrict__ inv, float* __restrict__ Aout,
    float* __restrict__ Oh, int KS) {
  __shared__ float stage[8736];
  int blk = blockIdx.x;
  int ksp = blk & (KS - 1);
  int rest = blk / KS;
  int qt = rest & 31, SL = rest >> 5;
  int b = SL / 6, t2 = SL % 6;
  int qb = qt * 16;
  int tid = threadIdx.x;
  int l = tid & 63, wv = tid >> 6, c = l & 15, g = l >> 4, thb = wv * 4;
  uint4 zz = make_uint4(0, 0, 0, 0);
  s16x8 Bq1[4], Bq2[4];
  #pragma unroll
  for (int j = 0; j < 4; ++j) {
    const uint4* row = (const uint4*)(Qp + ((size_t)(SL * 512 + qb + c) * 16 + thb + j) * 32);
    Bq1[j] = bc(row[g & 1]);
    Bq2[j] = bc(g < 2 ? row[2 + (g & 1)] : zz);
  }
  f32x4 O[4];
  #pragma unroll
  for (int j = 0; j < 4; ++j) O[j] = (f32x4){0.f, 0.f, 0.f, 0.f};

  int nch = 16 / KS;
  for (int cc = 0; cc < nch; ++cc) {
    int kch = ksp * (512 / KS) + cc * 32;
    #pragma unroll
    for (int e = 0; e < 2; ++e) {
      int kb = kch + e * 16;
      float4 m4 = *(const float4*)(mask + (size_t)(qb + c) * 512 + kb + 4 * g);
      float m[4] = {m4.x, m4.y, m4.z, m4.w};
      #pragma unroll
      for (int j = 0; j < 4; ++j) {
        const uint4* krow = (const uint4*)(Kp + ((size_t)(SL * 512 + kb + c) * 16 + thb + j) * 32);
        s16x8 A1 = bc(krow[g]);
        s16x8 A2 = bc(krow[g & 1]);
        f32x4 C = __builtin_amdgcn_mfma_f32_16x16x32_bf16(A1, Bq1[j], (f32x4){0.f,0.f,0.f,0.f}, 0, 0, 0);
        C = __builtin_amdgcn_mfma_f32_16x16x32_bf16(A2, Bq2[j], C, 0, 0, 0);
        float4 i4 = *(const float4*)(inv + (size_t)(SL * 16 + thb + j) * 512 + kb + 4 * g);
        float iv[4] = {i4.x, i4.y, i4.z, i4.w};
        #pragma unroll
        for (int r = 0; r < 4; ++r) {
          float Em = m[r] > 0.5f ? C[r] : MARKOFF_;
          float x = fminf(fmaxf(Em * INVSCALE_, -5.f), 5.f);
          float p = __expf(x) * iv[r];
          stage[(e * 16 + 4 * g + r) * 273 + c * 17 + thb + j] = p;
        }
      }
    }
    // A@V from stage (reads only own wave's th words -> no barrier needed)
    #pragma unroll
    for (int j = 0; j < 4; ++j) {
      int base = c * 17 + thb + j;
      ushort hs[8];
      #pragma unroll
      for (int m = 0; m < 8; ++m) hs[m] = f2bf(stage[(g * 8 + m) * 273 + base]);
      uint4 au = make_uint4((unsigned)hs[0] | ((unsigned)hs[1] << 16),
                            (unsigned)hs[2] | ((unsigned)hs[3] << 16),
                            (unsigned)hs[4] | ((unsigned)hs[5] << 16),
                            (unsigned)hs[6] | ((unsigned)hs[7] << 16));
      s16x8 a_op = bc(au);
      s16x8 v_op = bc(*(const uint4*)(Vt + ((size_t)(SL * 16 + thb + j) * 16 + c) * 512 + kch + g * 8));
      O[j] = __builtin_amdgcn_mfma_f32_16x16x32_bf16(a_op, v_op, O[j], 0, 0, 0);
    }
    __syncthreads();
    // coalesced A writeout: th innermost, each 4-lane group = one full 64B line
    #pragma unroll
    for (int it = 0; it < 8; ++it) {
      int f = tid + it * 256;
      int pr = f >> 2;
      int kk = pr & 31, q = pr >> 5;
      int m = f & 3;
      const float* sp = &stage[kk * 273 + q * 17 + m * 4];
      f32x4 v = {sp[0], sp[1], sp[2], sp[3]};
      size_t ga = ((size_t)(b * 512 + qb + q) * 512 + kch + kk) * 96 + t2 * 16 + m * 4;
      __builtin_nontemporal_store(v, (f32x4*)(Aout + ga));
    }
    __syncthreads();
  }
  #pragma unroll
  for (int j = 0; j < 4; ++j) {
    int th = thb + j, t = 2 * t2 + (th >> 3), h = th & 7;
    float* op = Oh + (size_t)ksp * 1572864;
    #pragma unroll
    for (int r = 0; r < 4; ++r)
      op[((size_t)(b * 512 + qb + 4 * g + r) * 12 + t) * 128 + h * 16 + c] = O[j][r];
  }
}

// ---------------- Kernel 5: out = Oh @ Wo^T + bo ----------------
__global__ __launch_bounds__(128) void k_outproj(
    const float* __restrict__ Oh, const float* __restrict__ Wo,
    const float* __restrict__ bo, float* __restrict__ out, int KS) {
  __shared__ float xr[12 * 128];
  int bn = blockIdx.x;
  int b = bn >> 9, n = bn & 511;
  int col = threadIdx.x;
  for (int i = col; i < 1536; i += 128) {
    float s = 0.f;
    for (int sl = 0; sl < KS; ++sl)
      s += Oh[(size_t)sl * 1572864 + (size_t)(b * 512 + n) * 1536 + i];
    xr[i] = s;
  }
  __syncthreads();
  float acc[12];
  float bias = bo[col];
  #pragma unroll
  for (int rr = 0; rr < 12; ++rr) acc[rr] = bias;
  const float4* wrow = reinterpret_cast<const float4*>(Wo + (size_t)col * 128);
  #pragma unroll 8
  for (int jc = 0; jc < 32; ++jc) {
    float4 w = wrow[jc];
    #pragma unroll
    for (int rr = 0; rr < 12; ++rr) {
      const float* x = &xr[rr * 128 + jc * 4];
      acc[rr] = fmaf(w.x, x[0], fmaf(w.y, x[1], fmaf(w.z, x[2], fmaf(w.w, x[3], acc[rr]))));
    }
  }
  size_t obase = ((size_t)(b * 512 + n)) * 1536;
  #pragma unroll
  for (int rr = 0; rr < 12; ++rr) out[obase + rr * 128 + col] = acc[rr];
}

extern "C" void kernel_launch(void* const* d_in, const int* in_sizes, int n_in,
                              void* d_out, int out_size, void* d_ws, size_t ws_size,
                              hipStream_t stream) {
  (void)in_sizes; (void)n_in; (void)out_size;
  const float* vals = (const float*)d_in[0];
  const float* keys = (const float*)d_in[1];
  const float* qry  = (const float*)d_in[2];
  const float* mask = (const float*)d_in[3];
  const float* Wv = (const float*)d_in[4];
  const float* Wk = (const float*)d_in[5];
  const float* Wq = (const float*)d_in[6];
  const float* Wo = (const float*)d_in[7];
  const float* bo = (const float*)d_in[8];
  float* out = (float*)d_out;
  float* Aout = out + 1572864;

  ushort* Qp = (ushort*)d_ws;           // 3,145,728 bf16
  ushort* Kp = Qp + 3145728;            // 3,145,728 bf16
  ushort* Vt = Kp + 3145728;            // 1,572,864 bf16
  float* cs  = (float*)(Vt + 1572864);  // 393,216 f32
  float* inv = cs + 393216;             // 98,304 f32
  float* Oh  = inv + 98304;             // KS x 1,572,864 f32

  const size_t BASE = 17694720;
  int KS = 1;
  if (ws_size >= BASE + 4ull * 6291456) KS = 4;
  else if (ws_size >= BASE + 2ull * 6291456) KS = 2;

  k_proj<<<192, 256, 0, stream>>>(vals, keys, qry, Wv, Wk, Wq, Qp, Kp, Vt);
  k_colsum<<<768, 256, 0, stream>>>(Qp, Kp, mask, cs);
  k_inv<<<384, 256, 0, stream>>>(cs, inv);
  k_attn<<<384 * KS, 256, 0, stream>>>(Qp, Kp, Vt, mask, inv, Aout, Oh, KS);
  k_outproj<<<1024, 128, 0, stream>>>(Oh, Wo, bo, out, KS);
}